// Round 1
// baseline (1096.050 us; speedup 1.0000x reference)
//
#include <hip/hip_runtime.h>

typedef __bf16 bf16;
typedef bf16 bf16x8 __attribute__((ext_vector_type(8)));
typedef float f32x4 __attribute__((ext_vector_type(4)));

#define NB 16
#define CLL 64
#define CHH 192
#define NPIX 16384

// ---------------- DWT: img(f32) -> X_ll, X_hh (bf16, [b][c][n]) + channel sums ----------------
__global__ void k_dwt(const float* __restrict__ img, bf16* __restrict__ xll,
                      bf16* __restrict__ xhh, float* __restrict__ sll, float* __restrict__ shh) {
    int i = blockIdx.x;            // DWT row 0..127
    int bc = blockIdx.y;           // b*64 + c
    int b = bc >> 6, c = bc & 63;
    int j = threadIdx.x;           // 0..127
    const float* base = img + ((size_t)bc << 16);
    float2 r0 = *(const float2*)(base + (size_t)(2 * i) * 256 + 2 * j);
    float2 r1 = *(const float2*)(base + (size_t)(2 * i + 1) * 256 + 2 * j);
    float a = r0.x, bb = r0.y, cc = r1.x, d = r1.y;
    float vll = (a + bb + cc + d) * 0.5f;
    float v1  = (a - bb + cc - d) * 0.5f;
    float v2  = (a + bb - cc - d) * 0.5f;
    float v3  = (a - bb - cc + d) * 0.5f;
    int n = i * 128 + j;
    xll[((size_t)b * CLL + c) * NPIX + n] = (bf16)vll;
    size_t hb = ((size_t)b * CHH + 3 * c) * NPIX + n;
    xhh[hb] = (bf16)v1; xhh[hb + NPIX] = (bf16)v2; xhh[hb + 2 * NPIX] = (bf16)v3;
    float s0 = vll, s1 = v1, s2 = v2, s3 = v3;
    for (int o = 32; o; o >>= 1) {
        s0 += __shfl_down(s0, o); s1 += __shfl_down(s1, o);
        s2 += __shfl_down(s2, o); s3 += __shfl_down(s3, o);
    }
    if ((threadIdx.x & 63) == 0) {
        atomicAdd(&sll[b * CLL + c], s0);
        atomicAdd(&shh[b * CHH + 3 * c + 0], s1);
        atomicAdd(&shh[b * CHH + 3 * c + 1], s2);
        atomicAdd(&shh[b * CHH + 3 * c + 2], s3);
    }
}

// ---------------- Gram: G[b] = X_b * X_b^T (bf16 MFMA, split-K, atomic fp32 accumulate) ------
template <int C, int SPLITK>
__global__ __launch_bounds__(256) void k_gram(const bf16* __restrict__ X, float* __restrict__ G) {
    constexpr int T = C / 64;
    int id = blockIdx.x;
    int sk = id % SPLITK; id /= SPLITK;
    int tj = id % T;      id /= T;
    int ti = id % T;      id /= T;
    int b = id;
    const bf16* Xb = X + (size_t)b * C * NPIX;
    int lane = threadIdx.x & 63, wv = threadIdx.x >> 6;
    int r0 = ti * 64 + (wv >> 1) * 32;
    int c0 = tj * 64 + (wv & 1) * 32;
    int g = lane >> 4, l15 = lane & 15;
    constexpr int KC = NPIX / SPLITK;
    f32x4 acc[2][2] = {};
    int k0 = sk * KC + g * 8;
    for (int kb = 0; kb < KC; kb += 32) {
        int kk = k0 + kb;
        bf16x8 a0 = *(const bf16x8*)(Xb + (size_t)(r0 + l15) * NPIX + kk);
        bf16x8 a1 = *(const bf16x8*)(Xb + (size_t)(r0 + 16 + l15) * NPIX + kk);
        bf16x8 b0 = *(const bf16x8*)(Xb + (size_t)(c0 + l15) * NPIX + kk);
        bf16x8 b1 = *(const bf16x8*)(Xb + (size_t)(c0 + 16 + l15) * NPIX + kk);
        acc[0][0] = __builtin_amdgcn_mfma_f32_16x16x32_bf16(a0, b0, acc[0][0], 0, 0, 0);
        acc[0][1] = __builtin_amdgcn_mfma_f32_16x16x32_bf16(a0, b1, acc[0][1], 0, 0, 0);
        acc[1][0] = __builtin_amdgcn_mfma_f32_16x16x32_bf16(a1, b0, acc[1][0], 0, 0, 0);
        acc[1][1] = __builtin_amdgcn_mfma_f32_16x16x32_bf16(a1, b1, acc[1][1], 0, 0, 0);
    }
    float* Gb = G + (size_t)b * C * C;
    #pragma unroll
    for (int rr = 0; rr < 2; rr++)
        #pragma unroll
        for (int c2 = 0; c2 < 2; c2++)
            #pragma unroll
            for (int rg = 0; rg < 4; rg++) {
                int row = r0 + rr * 16 + g * 4 + rg;   // m89-verified C/D layout
                int col = c0 + c2 * 16 + l15;
                atomicAdd(&Gb[(size_t)row * C + col], acc[rr][c2][rg]);
            }
}

// ---------------- P = w*G (per batch), plus row norm^2 and w·s ------------------------------
template <int C>
__global__ void k_pr(const float* __restrict__ G, const float* __restrict__ w,
                     const float* __restrict__ wb, const float* __restrict__ s,
                     float* __restrict__ P, float* __restrict__ nrm, float* __restrict__ wsum) {
    int b = blockIdx.y;
    int r0 = blockIdx.x * 16;
    int t = threadIdx.x, ti = t >> 4, tj = t & 15;
    int i = r0 + ti;
    const float* Gb = G + (size_t)b * C * C;
    constexpr int NJ = C / 16;
    float acc[NJ] = {};
    const float* wi = w + (size_t)i * C;
    for (int k = 0; k < C; k++) {
        float wk = wi[k];
        const float* Gk = Gb + (size_t)k * C;
        #pragma unroll
        for (int jj = 0; jj < NJ; jj++) acc[jj] += wk * Gk[tj + jj * 16];
    }
    float* Pb = P + (size_t)b * C * C;
    #pragma unroll
    for (int jj = 0; jj < NJ; jj++) Pb[(size_t)i * C + tj + jj * 16] = acc[jj];
    float np = 0.f;
    #pragma unroll
    for (int jj = 0; jj < NJ; jj++) np += acc[jj] * wi[tj + jj * 16];
    for (int o = 8; o; o >>= 1) np += __shfl_xor(np, o, 16);
    if (tj == 0) {
        float sd = 0.f; const float* sb = s + b * C;
        for (int k = 0; k < C; k++) sd += wi[k] * sb[k];
        float q2 = np + 2.f * wb[i] * sd + (float)NPIX * wb[i] * wb[i];
        nrm[b * C + i] = fmaxf(sqrtf(fmaxf(q2, 0.f)), 1e-12f);
        wsum[b * C + i] = sd;
    }
}

// ---------------- logits + softmax -> A, and av = A*vb --------------------------------------
template <int C>
__global__ void k_attn(const float* __restrict__ P, const float* __restrict__ kw,
                       const float* __restrict__ kb, const float* __restrict__ qb,
                       const float* __restrict__ qn, const float* __restrict__ kn,
                       const float* __restrict__ qs, const float* __restrict__ ks,
                       const float* __restrict__ vb, const float* __restrict__ temp,
                       float* __restrict__ A, float* __restrict__ av) {
    int b = blockIdx.y;
    int r0 = blockIdx.x * 16;
    int t = threadIdx.x, ti = t >> 4, tj = t & 15;
    int i = r0 + ti;
    constexpr int NJ = C / 16;
    const float* Pi = P + (size_t)b * C * C + (size_t)i * C;
    float L[NJ] = {};
    for (int k = 0; k < C; k++) {
        float pk = Pi[k];
        #pragma unroll
        for (int jj = 0; jj < NJ; jj++) L[jj] += pk * kw[(size_t)(tj + jj * 16) * C + k];
    }
    float qni = qn[b * C + i], qsi = qs[b * C + i], qbi = qb[i];
    float tmp = temp[0];
    #pragma unroll
    for (int jj = 0; jj < NJ; jj++) {
        int j = tj + jj * 16;
        float l = L[jj] + qsi * kb[j] + qbi * ks[b * C + j] + (float)NPIX * qbi * kb[j];
        L[jj] = l / (qni * kn[b * C + j]) * tmp;
    }
    float mx = -1e30f;
    #pragma unroll
    for (int jj = 0; jj < NJ; jj++) mx = fmaxf(mx, L[jj]);
    for (int o = 8; o; o >>= 1) mx = fmaxf(mx, __shfl_xor(mx, o, 16));
    float sum = 0.f;
    #pragma unroll
    for (int jj = 0; jj < NJ; jj++) { L[jj] = expf(L[jj] - mx); sum += L[jj]; }
    for (int o = 8; o; o >>= 1) sum += __shfl_xor(sum, o, 16);
    float inv = 1.f / sum;
    float* Ab = A + (size_t)b * C * C;
    float avp = 0.f;
    #pragma unroll
    for (int jj = 0; jj < NJ; jj++) {
        int j = tj + jj * 16;
        float a = L[jj] * inv;
        Ab[(size_t)i * C + j] = a;
        avp += a * vb[j];
    }
    for (int o = 8; o; o >>= 1) avp += __shfl_xor(avp, o, 16);
    if (tj == 0) av[b * C + i] = avp;
}

// ---------------- W = A*vw ------------------------------------------------------------------
template <int C>
__global__ void k_av(const float* __restrict__ A, const float* __restrict__ vw,
                     float* __restrict__ W) {
    int b = blockIdx.y;
    int r0 = blockIdx.x * 16;
    int t = threadIdx.x, ti = t >> 4, tj = t & 15;
    int i = r0 + ti;
    constexpr int NJ = C / 16;
    const float* Ai = A + (size_t)b * C * C + (size_t)i * C;
    float acc[NJ] = {};
    for (int k = 0; k < C; k++) {
        float a = Ai[k];
        const float* vr = vw + (size_t)k * C;
        #pragma unroll
        for (int jj = 0; jj < NJ; jj++) acc[jj] += a * vr[tj + jj * 16];
    }
    float* Wb = W + (size_t)b * C * C;
    #pragma unroll
    for (int jj = 0; jj < NJ; jj++) Wb[(size_t)i * C + tj + jj * 16] = acc[jj];
}

// ---------------- M = pw*W (bf16 out), mv = pw*av + pb --------------------------------------
template <int C>
__global__ void k_pm(const float* __restrict__ W, const float* __restrict__ pw,
                     const float* __restrict__ pb, const float* __restrict__ av,
                     bf16* __restrict__ M, float* __restrict__ mv) {
    int b = blockIdx.y;
    int r0 = blockIdx.x * 16;
    int t = threadIdx.x, ti = t >> 4, tj = t & 15;
    int i = r0 + ti;
    constexpr int NJ = C / 16;
    const float* pwi = pw + (size_t)i * C;
    const float* Wb = W + (size_t)b * C * C;
    float acc[NJ] = {};
    for (int k = 0; k < C; k++) {
        float p = pwi[k];
        const float* Wr = Wb + (size_t)k * C;
        #pragma unroll
        for (int jj = 0; jj < NJ; jj++) acc[jj] += p * Wr[tj + jj * 16];
    }
    bf16* Mb = M + (size_t)b * C * C;
    #pragma unroll
    for (int jj = 0; jj < NJ; jj++) Mb[(size_t)i * C + tj + jj * 16] = (bf16)acc[jj];
    if (tj == 0) {
        float m = pb[i];
        const float* avb = av + b * C;
        for (int k = 0; k < C; k++) m += pwi[k] * avb[k];
        mv[b * C + i] = m;
    }
}

// ---------------- Final: Y = M*X + mv (ll & hh), fused IDWT, write out ----------------------
__global__ __launch_bounds__(256) void k_final(const bf16* __restrict__ xll, const bf16* __restrict__ xhh,
                        const bf16* __restrict__ Mll, const bf16* __restrict__ Mhh,
                        const float* __restrict__ mvll, const float* __restrict__ mvhh,
                        float* __restrict__ out) {
    __shared__ alignas(16) float smemf[16384];   // 64 KB, aliased
    bf16* xtll = (bf16*)smemf;                    // [64 px][72]  (pad 8)
    bf16* xthh = (bf16*)((char*)smemf + 64 * 72 * 2);  // [64 px][200] (pad 8)
    float* Y = smemf;                             // [256 rows][64 px] after barrier
    int b = blockIdx.y, tile = blockIdx.x;
    int irow = tile >> 1, j0 = (tile & 1) << 6;
    int n0 = irow * 128 + j0;
    int t = threadIdx.x;
    const bf16* Xl = xll + (size_t)b * CLL * NPIX;
    const bf16* Xh = xhh + (size_t)b * CHH * NPIX;
    for (int task = t; task < 512; task += 256) {      // ll: 64 rows x 8 chunks
        int row = task >> 3, ch = task & 7;
        bf16x8 v = *(const bf16x8*)(Xl + (size_t)row * NPIX + n0 + ch * 8);
        #pragma unroll
        for (int p = 0; p < 8; p++) xtll[(ch * 8 + p) * 72 + row] = v[p];
    }
    for (int task = t; task < 1536; task += 256) {     // hh: 192 rows x 8 chunks
        int row = task >> 3, ch = task & 7;
        bf16x8 v = *(const bf16x8*)(Xh + (size_t)row * NPIX + n0 + ch * 8);
        #pragma unroll
        for (int p = 0; p < 8; p++) xthh[(ch * 8 + p) * 200 + row] = v[p];
    }
    __syncthreads();
    int wv = t >> 6, lane = t & 63, g = lane >> 4, l15 = lane & 15;
    f32x4 acc[4][4] = {};
    if (wv == 0) {
        const bf16* M = Mll + (size_t)b * CLL * CLL;
        for (int kb = 0; kb < CLL; kb += 32) {
            bf16x8 af[4], bfr[4];
            #pragma unroll
            for (int r = 0; r < 4; r++) af[r] = *(const bf16x8*)(M + (size_t)(r * 16 + l15) * CLL + kb + g * 8);
            #pragma unroll
            for (int c2 = 0; c2 < 4; c2++) bfr[c2] = *(const bf16x8*)(xtll + (c2 * 16 + l15) * 72 + kb + g * 8);
            #pragma unroll
            for (int r = 0; r < 4; r++)
                #pragma unroll
                for (int c2 = 0; c2 < 4; c2++)
                    acc[r][c2] = __builtin_amdgcn_mfma_f32_16x16x32_bf16(af[r], bfr[c2], acc[r][c2], 0, 0, 0);
        }
    } else {
        int wr = (wv - 1) * 64;
        const bf16* M = Mhh + (size_t)b * CHH * CHH;
        for (int kb = 0; kb < CHH; kb += 32) {
            bf16x8 af[4], bfr[4];
            #pragma unroll
            for (int r = 0; r < 4; r++) af[r] = *(const bf16x8*)(M + (size_t)(wr + r * 16 + l15) * CHH + kb + g * 8);
            #pragma unroll
            for (int c2 = 0; c2 < 4; c2++) bfr[c2] = *(const bf16x8*)(xthh + (c2 * 16 + l15) * 200 + kb + g * 8);
            #pragma unroll
            for (int r = 0; r < 4; r++)
                #pragma unroll
                for (int c2 = 0; c2 < 4; c2++)
                    acc[r][c2] = __builtin_amdgcn_mfma_f32_16x16x32_bf16(af[r], bfr[c2], acc[r][c2], 0, 0, 0);
        }
    }
    __syncthreads();   // staging reads done; smem becomes Y
    {
        int rbase = (wv == 0) ? 0 : 64 + (wv - 1) * 64;
        #pragma unroll
        for (int r = 0; r < 4; r++)
            #pragma unroll
            for (int c2 = 0; c2 < 4; c2++)
                #pragma unroll
                for (int rg = 0; rg < 4; rg++) {
                    int rl = r * 16 + g * 4 + rg;                 // row within wave's 64
                    float bias = (wv == 0) ? mvll[b * CLL + rl]
                                           : mvhh[b * CHH + (wv - 1) * 64 + rl];
                    Y[(rbase + rl) * 64 + c2 * 16 + l15] = acc[r][c2][rg] + bias;
                }
    }
    __syncthreads();
    int p = t & 63, cg = t >> 6;
    float* ob = out + ((size_t)b * CLL) * 65536;
    for (int it = 0; it < 16; it++) {
        int c = it * 4 + cg;
        float ll = Y[c * 64 + p];
        float h1 = Y[(64 + 3 * c + 0) * 64 + p];
        float h2 = Y[(64 + 3 * c + 1) * 64 + p];
        float h3 = Y[(64 + 3 * c + 2) * 64 + p];
        float a  = (ll + h1 + h2 + h3) * 0.5f;
        float bb = (ll - h1 + h2 - h3) * 0.5f;
        float cc = (ll + h1 - h2 - h3) * 0.5f;
        float d  = (ll - h1 - h2 + h3) * 0.5f;
        int jj = j0 + p;
        float2* o0 = (float2*)(ob + ((size_t)c * 256 + 2 * irow) * 256 + 2 * jj);
        float2* o1 = (float2*)(ob + ((size_t)c * 256 + 2 * irow + 1) * 256 + 2 * jj);
        *o0 = make_float2(a, bb);
        *o1 = make_float2(cc, d);
    }
}

extern "C" void kernel_launch(void* const* d_in, const int* in_sizes, int n_in,
                              void* d_out, int out_size, void* d_ws, size_t ws_size,
                              hipStream_t stream) {
    const float* img    = (const float*)d_in[0];
    // dict order is interleaved: ll_qw, h_qw, ll_qb, h_qb, ...
    const float* ll_qw = (const float*)d_in[1];  const float* h_qw = (const float*)d_in[2];
    const float* ll_qb = (const float*)d_in[3];  const float* h_qb = (const float*)d_in[4];
    const float* ll_kw = (const float*)d_in[5];  const float* h_kw = (const float*)d_in[6];
    const float* ll_kb = (const float*)d_in[7];  const float* h_kb = (const float*)d_in[8];
    const float* ll_vw = (const float*)d_in[9];  const float* h_vw = (const float*)d_in[10];
    const float* ll_vb = (const float*)d_in[11]; const float* h_vb = (const float*)d_in[12];
    const float* ll_pw = (const float*)d_in[13]; const float* h_pw = (const float*)d_in[14];
    const float* ll_pb = (const float*)d_in[15]; const float* h_pb = (const float*)d_in[16];
    const float* ll_tp = (const float*)d_in[17]; const float* h_tp = (const float*)d_in[18];
    float* out = (float*)d_out;

    char* ws = (char*)d_ws;
    size_t off = 0;
    auto alloc = [&](size_t sz) { char* p = ws + off; off += (sz + 255) & ~(size_t)255; return p; };
    bf16*  xll  = (bf16*) alloc((size_t)NB * CLL * NPIX * 2);
    bf16*  xhh  = (bf16*) alloc((size_t)NB * CHH * NPIX * 2);
    char*  zb   = ws + off;                       // zero-init region start
    float* sll  = (float*)alloc(NB * CLL * 4);
    float* shh  = (float*)alloc(NB * CHH * 4);
    float* Gll  = (float*)alloc((size_t)NB * CLL * CLL * 4);
    float* Ghh  = (float*)alloc((size_t)NB * CHH * CHH * 4);
    size_t zsz  = (size_t)((ws + off) - zb);
    float* Pll  = (float*)alloc((size_t)NB * CLL * CLL * 4);
    float* Phh  = (float*)alloc((size_t)NB * CHH * CHH * 4);
    float* Rll  = (float*)alloc((size_t)NB * CLL * CLL * 4);
    float* Rhh  = (float*)alloc((size_t)NB * CHH * CHH * 4);
    float* qnll = (float*)alloc(NB * CLL * 4);   float* qnhh = (float*)alloc(NB * CHH * 4);
    float* knll = (float*)alloc(NB * CLL * 4);   float* knhh = (float*)alloc(NB * CHH * 4);
    float* qsll = (float*)alloc(NB * CLL * 4);   float* qshh = (float*)alloc(NB * CHH * 4);
    float* ksll = (float*)alloc(NB * CLL * 4);   float* kshh = (float*)alloc(NB * CHH * 4);
    float* All  = (float*)alloc((size_t)NB * CLL * CLL * 4);
    float* Ahh  = (float*)alloc((size_t)NB * CHH * CHH * 4);
    float* avll = (float*)alloc(NB * CLL * 4);   float* avhh = (float*)alloc(NB * CHH * 4);
    float* Wll  = (float*)alloc((size_t)NB * CLL * CLL * 4);
    float* Whh  = (float*)alloc((size_t)NB * CHH * CHH * 4);
    bf16*  Mll  = (bf16*) alloc((size_t)NB * CLL * CLL * 2);
    bf16*  Mhh  = (bf16*) alloc((size_t)NB * CHH * CHH * 2);
    float* mvll = (float*)alloc(NB * CLL * 4);   float* mvhh = (float*)alloc(NB * CHH * 4);

    hipMemsetAsync(zb, 0, zsz, stream);

    k_dwt<<<dim3(128, NB * 64), 128, 0, stream>>>(img, xll, xhh, sll, shh);

    k_gram<CLL, 8><<<NB * 1 * 8, 256, 0, stream>>>(xll, Gll);
    k_gram<CHH, 8><<<NB * 9 * 8, 256, 0, stream>>>(xhh, Ghh);

    k_pr<CLL><<<dim3(CLL / 16, NB), 256, 0, stream>>>(Gll, ll_qw, ll_qb, sll, Pll, qnll, qsll);
    k_pr<CLL><<<dim3(CLL / 16, NB), 256, 0, stream>>>(Gll, ll_kw, ll_kb, sll, Rll, knll, ksll);
    k_pr<CHH><<<dim3(CHH / 16, NB), 256, 0, stream>>>(Ghh, h_qw, h_qb, shh, Phh, qnhh, qshh);
    k_pr<CHH><<<dim3(CHH / 16, NB), 256, 0, stream>>>(Ghh, h_kw, h_kb, shh, Rhh, knhh, kshh);

    k_attn<CLL><<<dim3(CLL / 16, NB), 256, 0, stream>>>(Pll, ll_kw, ll_kb, ll_qb, qnll, knll,
                                                        qsll, ksll, ll_vb, ll_tp, All, avll);
    k_attn<CHH><<<dim3(CHH / 16, NB), 256, 0, stream>>>(Phh, h_kw, h_kb, h_qb, qnhh, knhh,
                                                        qshh, kshh, h_vb, h_tp, Ahh, avhh);

    k_av<CLL><<<dim3(CLL / 16, NB), 256, 0, stream>>>(All, ll_vw, Wll);
    k_av<CHH><<<dim3(CHH / 16, NB), 256, 0, stream>>>(Ahh, h_vw, Whh);

    k_pm<CLL><<<dim3(CLL / 16, NB), 256, 0, stream>>>(Wll, ll_pw, ll_pb, avll, Mll, mvll);
    k_pm<CHH><<<dim3(CHH / 16, NB), 256, 0, stream>>>(Whh, h_pw, h_pb, avhh, Mhh, mvhh);

    k_final<<<dim3(256, NB), 256, 0, stream>>>(xll, xhh, Mll, Mhh, mvll, mvhh, out);
}

// Round 2
// 668.229 us; speedup vs baseline: 1.6402x; 1.6402x over previous
//
#include <hip/hip_runtime.h>

typedef __bf16 bf16;
typedef bf16 bf16x8 __attribute__((ext_vector_type(8)));
typedef float f32x4 __attribute__((ext_vector_type(4)));

#define NB 16
#define CLL 64
#define CHH 192
#define NPIX 16384

// ---------------- DWT: img(f32) -> X_ll, X_hh (bf16, [b][c][n]) + channel sums ----------------
// 256 thr/block; each thread: 8 output px (reads 2x64B contiguous, writes 4x bf16x8).
__global__ __launch_bounds__(256) void k_dwt(const float* __restrict__ img, bf16* __restrict__ xll,
                      bf16* __restrict__ xhh, float* __restrict__ sll, float* __restrict__ shh) {
    int bc = blockIdx.y;           // b*64 + c
    int b = bc >> 6, c = bc & 63;
    int t = threadIdx.x;
    int r = blockIdx.x * 16 + (t >> 4);   // out row 0..127
    int q = t & 15;                        // 8-px col group
    const float* p0 = img + ((size_t)bc << 16) + (size_t)(2 * r) * 256 + 16 * q;
    const float* p1 = p0 + 256;
    float4 e0[4], e1[4];
    #pragma unroll
    for (int l = 0; l < 4; l++) { e0[l] = ((const float4*)p0)[l]; e1[l] = ((const float4*)p1)[l]; }
    const float* f0 = (const float*)e0;
    const float* f1 = (const float*)e1;
    bf16x8 vll, v1, v2, v3;
    float s0 = 0.f, s1 = 0.f, s2 = 0.f, s3 = 0.f;
    #pragma unroll
    for (int p = 0; p < 8; p++) {
        float a = f0[2 * p], bb = f0[2 * p + 1], cc = f1[2 * p], d = f1[2 * p + 1];
        float wll = (a + bb + cc + d) * 0.5f;
        float w1  = (a - bb + cc - d) * 0.5f;
        float w2  = (a + bb - cc - d) * 0.5f;
        float w3  = (a - bb - cc + d) * 0.5f;
        vll[p] = (bf16)wll; v1[p] = (bf16)w1; v2[p] = (bf16)w2; v3[p] = (bf16)w3;
        s0 += wll; s1 += w1; s2 += w2; s3 += w3;
    }
    size_t n = (size_t)r * 128 + 8 * q;
    *(bf16x8*)(xll + ((size_t)b * CLL + c) * NPIX + n) = vll;
    size_t hb = ((size_t)b * CHH + 3 * c) * NPIX + n;
    *(bf16x8*)(xhh + hb) = v1;
    *(bf16x8*)(xhh + hb + NPIX) = v2;
    *(bf16x8*)(xhh + hb + 2 * NPIX) = v3;
    for (int o = 32; o; o >>= 1) {
        s0 += __shfl_down(s0, o); s1 += __shfl_down(s1, o);
        s2 += __shfl_down(s2, o); s3 += __shfl_down(s3, o);
    }
    if ((t & 63) == 0) {
        atomicAdd(&sll[b * CLL + c], s0);
        atomicAdd(&shh[b * CHH + 3 * c + 0], s1);
        atomicAdd(&shh[b * CHH + 3 * c + 1], s2);
        atomicAdd(&shh[b * CHH + 3 * c + 2], s3);
    }
}

// ---------------- Gram: G[b] = X_b * X_b^T (bf16 MFMA, split-K, atomic fp32 accumulate) ------
template <int C, int SPLITK>
__global__ __launch_bounds__(256) void k_gram(const bf16* __restrict__ X, float* __restrict__ G) {
    constexpr int T = C / 64;
    int id = blockIdx.x;
    int sk = id % SPLITK; id /= SPLITK;
    int tj = id % T;      id /= T;
    int ti = id % T;      id /= T;
    int b = id;
    const bf16* Xb = X + (size_t)b * C * NPIX;
    int lane = threadIdx.x & 63, wv = threadIdx.x >> 6;
    int r0 = ti * 64 + (wv >> 1) * 32;
    int c0 = tj * 64 + (wv & 1) * 32;
    int g = lane >> 4, l15 = lane & 15;
    constexpr int KC = NPIX / SPLITK;
    f32x4 acc[2][2] = {};
    int k0 = sk * KC + g * 8;
    for (int kb = 0; kb < KC; kb += 32) {
        int kk = k0 + kb;
        bf16x8 a0 = *(const bf16x8*)(Xb + (size_t)(r0 + l15) * NPIX + kk);
        bf16x8 a1 = *(const bf16x8*)(Xb + (size_t)(r0 + 16 + l15) * NPIX + kk);
        bf16x8 b0 = *(const bf16x8*)(Xb + (size_t)(c0 + l15) * NPIX + kk);
        bf16x8 b1 = *(const bf16x8*)(Xb + (size_t)(c0 + 16 + l15) * NPIX + kk);
        acc[0][0] = __builtin_amdgcn_mfma_f32_16x16x32_bf16(a0, b0, acc[0][0], 0, 0, 0);
        acc[0][1] = __builtin_amdgcn_mfma_f32_16x16x32_bf16(a0, b1, acc[0][1], 0, 0, 0);
        acc[1][0] = __builtin_amdgcn_mfma_f32_16x16x32_bf16(a1, b0, acc[1][0], 0, 0, 0);
        acc[1][1] = __builtin_amdgcn_mfma_f32_16x16x32_bf16(a1, b1, acc[1][1], 0, 0, 0);
    }
    float* Gb = G + (size_t)b * C * C;
    #pragma unroll
    for (int rr = 0; rr < 2; rr++)
        #pragma unroll
        for (int c2 = 0; c2 < 2; c2++)
            #pragma unroll
            for (int rg = 0; rg < 4; rg++) {
                int row = r0 + rr * 16 + g * 4 + rg;   // m89-verified C/D layout
                int col = c0 + c2 * 16 + l15;
                atomicAdd(&Gb[(size_t)row * C + col], acc[rr][c2][rg]);
            }
}

// ---------------- P = w*G (per batch), plus row norm^2 and w·s ------------------------------
template <int C>
__global__ void k_pr(const float* __restrict__ G, const float* __restrict__ w,
                     const float* __restrict__ wb, const float* __restrict__ s,
                     float* __restrict__ P, float* __restrict__ nrm, float* __restrict__ wsum) {
    int b = blockIdx.y;
    int r0 = blockIdx.x * 16;
    int t = threadIdx.x, ti = t >> 4, tj = t & 15;
    int i = r0 + ti;
    const float* Gb = G + (size_t)b * C * C;
    constexpr int NJ = C / 16;
    float acc[NJ] = {};
    const float* wi = w + (size_t)i * C;
    for (int k = 0; k < C; k++) {
        float wk = wi[k];
        const float* Gk = Gb + (size_t)k * C;
        #pragma unroll
        for (int jj = 0; jj < NJ; jj++) acc[jj] += wk * Gk[tj + jj * 16];
    }
    float* Pb = P + (size_t)b * C * C;
    #pragma unroll
    for (int jj = 0; jj < NJ; jj++) Pb[(size_t)i * C + tj + jj * 16] = acc[jj];
    float np = 0.f;
    #pragma unroll
    for (int jj = 0; jj < NJ; jj++) np += acc[jj] * wi[tj + jj * 16];
    for (int o = 8; o; o >>= 1) np += __shfl_xor(np, o, 16);
    if (tj == 0) {
        float sd = 0.f; const float* sb = s + b * C;
        for (int k = 0; k < C; k++) sd += wi[k] * sb[k];
        float q2 = np + 2.f * wb[i] * sd + (float)NPIX * wb[i] * wb[i];
        nrm[b * C + i] = fmaxf(sqrtf(fmaxf(q2, 0.f)), 1e-12f);
        wsum[b * C + i] = sd;
    }
}

// ---------------- logits + softmax -> A, and av = A*vb --------------------------------------
template <int C>
__global__ void k_attn(const float* __restrict__ P, const float* __restrict__ kw,
                       const float* __restrict__ kb, const float* __restrict__ qb,
                       const float* __restrict__ qn, const float* __restrict__ kn,
                       const float* __restrict__ qs, const float* __restrict__ ks,
                       const float* __restrict__ vb, const float* __restrict__ temp,
                       float* __restrict__ A, float* __restrict__ av) {
    int b = blockIdx.y;
    int r0 = blockIdx.x * 16;
    int t = threadIdx.x, ti = t >> 4, tj = t & 15;
    int i = r0 + ti;
    constexpr int NJ = C / 16;
    const float* Pi = P + (size_t)b * C * C + (size_t)i * C;
    float L[NJ] = {};
    for (int k = 0; k < C; k++) {
        float pk = Pi[k];
        #pragma unroll
        for (int jj = 0; jj < NJ; jj++) L[jj] += pk * kw[(size_t)(tj + jj * 16) * C + k];
    }
    float qni = qn[b * C + i], qsi = qs[b * C + i], qbi = qb[i];
    float tmp = temp[0];
    #pragma unroll
    for (int jj = 0; jj < NJ; jj++) {
        int j = tj + jj * 16;
        float l = L[jj] + qsi * kb[j] + qbi * ks[b * C + j] + (float)NPIX * qbi * kb[j];
        L[jj] = l / (qni * kn[b * C + j]) * tmp;
    }
    float mx = -1e30f;
    #pragma unroll
    for (int jj = 0; jj < NJ; jj++) mx = fmaxf(mx, L[jj]);
    for (int o = 8; o; o >>= 1) mx = fmaxf(mx, __shfl_xor(mx, o, 16));
    float sum = 0.f;
    #pragma unroll
    for (int jj = 0; jj < NJ; jj++) { L[jj] = expf(L[jj] - mx); sum += L[jj]; }
    for (int o = 8; o; o >>= 1) sum += __shfl_xor(sum, o, 16);
    float inv = 1.f / sum;
    float* Ab = A + (size_t)b * C * C;
    float avp = 0.f;
    #pragma unroll
    for (int jj = 0; jj < NJ; jj++) {
        int j = tj + jj * 16;
        float a = L[jj] * inv;
        Ab[(size_t)i * C + j] = a;
        avp += a * vb[j];
    }
    for (int o = 8; o; o >>= 1) avp += __shfl_xor(avp, o, 16);
    if (tj == 0) av[b * C + i] = avp;
}

// ---------------- W = A*vw ------------------------------------------------------------------
template <int C>
__global__ void k_av(const float* __restrict__ A, const float* __restrict__ vw,
                     float* __restrict__ W) {
    int b = blockIdx.y;
    int r0 = blockIdx.x * 16;
    int t = threadIdx.x, ti = t >> 4, tj = t & 15;
    int i = r0 + ti;
    constexpr int NJ = C / 16;
    const float* Ai = A + (size_t)b * C * C + (size_t)i * C;
    float acc[NJ] = {};
    for (int k = 0; k < C; k++) {
        float a = Ai[k];
        const float* vr = vw + (size_t)k * C;
        #pragma unroll
        for (int jj = 0; jj < NJ; jj++) acc[jj] += a * vr[tj + jj * 16];
    }
    float* Wb = W + (size_t)b * C * C;
    #pragma unroll
    for (int jj = 0; jj < NJ; jj++) Wb[(size_t)i * C + tj + jj * 16] = acc[jj];
}

// ---------------- M = pw*W (bf16 out), mv = pw*av + pb --------------------------------------
template <int C>
__global__ void k_pm(const float* __restrict__ W, const float* __restrict__ pw,
                     const float* __restrict__ pb, const float* __restrict__ av,
                     bf16* __restrict__ M, float* __restrict__ mv) {
    int b = blockIdx.y;
    int r0 = blockIdx.x * 16;
    int t = threadIdx.x, ti = t >> 4, tj = t & 15;
    int i = r0 + ti;
    constexpr int NJ = C / 16;
    const float* pwi = pw + (size_t)i * C;
    const float* Wb = W + (size_t)b * C * C;
    float acc[NJ] = {};
    for (int k = 0; k < C; k++) {
        float p = pwi[k];
        const float* Wr = Wb + (size_t)k * C;
        #pragma unroll
        for (int jj = 0; jj < NJ; jj++) acc[jj] += p * Wr[tj + jj * 16];
    }
    bf16* Mb = M + (size_t)b * C * C;
    #pragma unroll
    for (int jj = 0; jj < NJ; jj++) Mb[(size_t)i * C + tj + jj * 16] = (bf16)acc[jj];
    if (tj == 0) {
        float m = pb[i];
        const float* avb = av + b * C;
        for (int k = 0; k < C; k++) m += pwi[k] * avb[k];
        mv[b * C + i] = m;
    }
}

// ---------------- Final: Y = M*X + mv (ll & hh), fused IDWT, write out ----------------------
__global__ __launch_bounds__(256) void k_final(const bf16* __restrict__ xll, const bf16* __restrict__ xhh,
                        const bf16* __restrict__ Mll, const bf16* __restrict__ Mhh,
                        const float* __restrict__ mvll, const float* __restrict__ mvhh,
                        float* __restrict__ out) {
    __shared__ alignas(16) float smemf[16384];   // 64 KB, aliased
    bf16* xtll = (bf16*)smemf;                    // [64 px][72]  (pad 8)
    bf16* xthh = (bf16*)((char*)smemf + 64 * 72 * 2);  // [64 px][200] (pad 8)
    float* Y = smemf;                             // [256 rows][64 px] after barrier
    int b = blockIdx.y, tile = blockIdx.x;
    int irow = tile >> 1, j0 = (tile & 1) << 6;
    int n0 = irow * 128 + j0;
    int t = threadIdx.x;
    const bf16* Xl = xll + (size_t)b * CLL * NPIX;
    const bf16* Xh = xhh + (size_t)b * CHH * NPIX;
    for (int task = t; task < 512; task += 256) {      // ll: 64 rows x 8 chunks
        int row = task >> 3, ch = task & 7;
        bf16x8 v = *(const bf16x8*)(Xl + (size_t)row * NPIX + n0 + ch * 8);
        #pragma unroll
        for (int p = 0; p < 8; p++) xtll[(ch * 8 + p) * 72 + row] = v[p];
    }
    for (int task = t; task < 1536; task += 256) {     // hh: 192 rows x 8 chunks
        int row = task >> 3, ch = task & 7;
        bf16x8 v = *(const bf16x8*)(Xh + (size_t)row * NPIX + n0 + ch * 8);
        #pragma unroll
        for (int p = 0; p < 8; p++) xthh[(ch * 8 + p) * 200 + row] = v[p];
    }
    __syncthreads();
    int wv = t >> 6, lane = t & 63, g = lane >> 4, l15 = lane & 15;
    f32x4 acc[4][4] = {};
    if (wv == 0) {
        const bf16* M = Mll + (size_t)b * CLL * CLL;
        for (int kb = 0; kb < CLL; kb += 32) {
            bf16x8 af[4], bfr[4];
            #pragma unroll
            for (int r = 0; r < 4; r++) af[r] = *(const bf16x8*)(M + (size_t)(r * 16 + l15) * CLL + kb + g * 8);
            #pragma unroll
            for (int c2 = 0; c2 < 4; c2++) bfr[c2] = *(const bf16x8*)(xtll + (c2 * 16 + l15) * 72 + kb + g * 8);
            #pragma unroll
            for (int r = 0; r < 4; r++)
                #pragma unroll
                for (int c2 = 0; c2 < 4; c2++)
                    acc[r][c2] = __builtin_amdgcn_mfma_f32_16x16x32_bf16(af[r], bfr[c2], acc[r][c2], 0, 0, 0);
        }
    } else {
        int wr = (wv - 1) * 64;
        const bf16* M = Mhh + (size_t)b * CHH * CHH;
        for (int kb = 0; kb < CHH; kb += 32) {
            bf16x8 af[4], bfr[4];
            #pragma unroll
            for (int r = 0; r < 4; r++) af[r] = *(const bf16x8*)(M + (size_t)(wr + r * 16 + l15) * CHH + kb + g * 8);
            #pragma unroll
            for (int c2 = 0; c2 < 4; c2++) bfr[c2] = *(const bf16x8*)(xthh + (c2 * 16 + l15) * 200 + kb + g * 8);
            #pragma unroll
            for (int r = 0; r < 4; r++)
                #pragma unroll
                for (int c2 = 0; c2 < 4; c2++)
                    acc[r][c2] = __builtin_amdgcn_mfma_f32_16x16x32_bf16(af[r], bfr[c2], acc[r][c2], 0, 0, 0);
        }
    }
    __syncthreads();   // staging reads done; smem becomes Y
    {
        int rbase = (wv == 0) ? 0 : 64 + (wv - 1) * 64;
        #pragma unroll
        for (int r = 0; r < 4; r++)
            #pragma unroll
            for (int c2 = 0; c2 < 4; c2++)
                #pragma unroll
                for (int rg = 0; rg < 4; rg++) {
                    int rl = r * 16 + g * 4 + rg;                 // row within wave's 64
                    float bias = (wv == 0) ? mvll[b * CLL + rl]
                                           : mvhh[b * CHH + (wv - 1) * 64 + rl];
                    Y[(rbase + rl) * 64 + c2 * 16 + l15] = acc[r][c2][rg] + bias;
                }
    }
    __syncthreads();
    int p = t & 63, cg = t >> 6;
    float* ob = out + ((size_t)b * CLL) * 65536;
    for (int it = 0; it < 16; it++) {
        int c = it * 4 + cg;
        float ll = Y[c * 64 + p];
        float h1 = Y[(64 + 3 * c + 0) * 64 + p];
        float h2 = Y[(64 + 3 * c + 1) * 64 + p];
        float h3 = Y[(64 + 3 * c + 2) * 64 + p];
        float a  = (ll + h1 + h2 + h3) * 0.5f;
        float bb = (ll - h1 + h2 - h3) * 0.5f;
        float cc = (ll + h1 - h2 - h3) * 0.5f;
        float d  = (ll - h1 - h2 + h3) * 0.5f;
        int jj = j0 + p;
        float2* o0 = (float2*)(ob + ((size_t)c * 256 + 2 * irow) * 256 + 2 * jj);
        float2* o1 = (float2*)(ob + ((size_t)c * 256 + 2 * irow + 1) * 256 + 2 * jj);
        *o0 = make_float2(a, bb);
        *o1 = make_float2(cc, d);
    }
}

extern "C" void kernel_launch(void* const* d_in, const int* in_sizes, int n_in,
                              void* d_out, int out_size, void* d_ws, size_t ws_size,
                              hipStream_t stream) {
    const float* img    = (const float*)d_in[0];
    // dict order is interleaved: ll_qw, h_qw, ll_qb, h_qb, ...
    const float* ll_qw = (const float*)d_in[1];  const float* h_qw = (const float*)d_in[2];
    const float* ll_qb = (const float*)d_in[3];  const float* h_qb = (const float*)d_in[4];
    const float* ll_kw = (const float*)d_in[5];  const float* h_kw = (const float*)d_in[6];
    const float* ll_kb = (const float*)d_in[7];  const float* h_kb = (const float*)d_in[8];
    const float* ll_vw = (const float*)d_in[9];  const float* h_vw = (const float*)d_in[10];
    const float* ll_vb = (const float*)d_in[11]; const float* h_vb = (const float*)d_in[12];
    const float* ll_pw = (const float*)d_in[13]; const float* h_pw = (const float*)d_in[14];
    const float* ll_pb = (const float*)d_in[15]; const float* h_pb = (const float*)d_in[16];
    const float* ll_tp = (const float*)d_in[17]; const float* h_tp = (const float*)d_in[18];
    float* out = (float*)d_out;

    char* ws = (char*)d_ws;
    size_t off = 0;
    auto alloc = [&](size_t sz) { char* p = ws + off; off += (sz + 255) & ~(size_t)255; return p; };
    bf16*  xll  = (bf16*) alloc((size_t)NB * CLL * NPIX * 2);
    bf16*  xhh  = (bf16*) alloc((size_t)NB * CHH * NPIX * 2);
    char*  zb   = ws + off;                       // zero-init region start
    float* sll  = (float*)alloc(NB * CLL * 4);
    float* shh  = (float*)alloc(NB * CHH * 4);
    float* Gll  = (float*)alloc((size_t)NB * CLL * CLL * 4);
    float* Ghh  = (float*)alloc((size_t)NB * CHH * CHH * 4);
    size_t zsz  = (size_t)((ws + off) - zb);
    float* Pll  = (float*)alloc((size_t)NB * CLL * CLL * 4);
    float* Phh  = (float*)alloc((size_t)NB * CHH * CHH * 4);
    float* Rll  = (float*)alloc((size_t)NB * CLL * CLL * 4);
    float* Rhh  = (float*)alloc((size_t)NB * CHH * CHH * 4);
    float* qnll = (float*)alloc(NB * CLL * 4);   float* qnhh = (float*)alloc(NB * CHH * 4);
    float* knll = (float*)alloc(NB * CLL * 4);   float* knhh = (float*)alloc(NB * CHH * 4);
    float* qsll = (float*)alloc(NB * CLL * 4);   float* qshh = (float*)alloc(NB * CHH * 4);
    float* ksll = (float*)alloc(NB * CLL * 4);   float* kshh = (float*)alloc(NB * CHH * 4);
    float* All  = (float*)alloc((size_t)NB * CLL * CLL * 4);
    float* Ahh  = (float*)alloc((size_t)NB * CHH * CHH * 4);
    float* avll = (float*)alloc(NB * CLL * 4);   float* avhh = (float*)alloc(NB * CHH * 4);
    float* Wll  = (float*)alloc((size_t)NB * CLL * CLL * 4);
    float* Whh  = (float*)alloc((size_t)NB * CHH * CHH * 4);
    bf16*  Mll  = (bf16*) alloc((size_t)NB * CLL * CLL * 2);
    bf16*  Mhh  = (bf16*) alloc((size_t)NB * CHH * CHH * 2);
    float* mvll = (float*)alloc(NB * CLL * 4);   float* mvhh = (float*)alloc(NB * CHH * 4);

    hipMemsetAsync(zb, 0, zsz, stream);

    k_dwt<<<dim3(8, NB * 64), 256, 0, stream>>>(img, xll, xhh, sll, shh);

    k_gram<CLL, 8><<<NB * 1 * 8, 256, 0, stream>>>(xll, Gll);
    k_gram<CHH, 8><<<NB * 9 * 8, 256, 0, stream>>>(xhh, Ghh);

    k_pr<CLL><<<dim3(CLL / 16, NB), 256, 0, stream>>>(Gll, ll_qw, ll_qb, sll, Pll, qnll, qsll);
    k_pr<CLL><<<dim3(CLL / 16, NB), 256, 0, stream>>>(Gll, ll_kw, ll_kb, sll, Rll, knll, ksll);
    k_pr<CHH><<<dim3(CHH / 16, NB), 256, 0, stream>>>(Ghh, h_qw, h_qb, shh, Phh, qnhh, qshh);
    k_pr<CHH><<<dim3(CHH / 16, NB), 256, 0, stream>>>(Ghh, h_kw, h_kb, shh, Rhh, knhh, kshh);

    k_attn<CLL><<<dim3(CLL / 16, NB), 256, 0, stream>>>(Pll, ll_kw, ll_kb, ll_qb, qnll, knll,
                                                        qsll, ksll, ll_vb, ll_tp, All, avll);
    k_attn<CHH><<<dim3(CHH / 16, NB), 256, 0, stream>>>(Phh, h_kw, h_kb, h_qb, qnhh, knhh,
                                                        qshh, kshh, h_vb, h_tp, Ahh, avhh);

    k_av<CLL><<<dim3(CLL / 16, NB), 256, 0, stream>>>(All, ll_vw, Wll);
    k_av<CHH><<<dim3(CHH / 16, NB), 256, 0, stream>>>(Ahh, h_vw, Whh);

    k_pm<CLL><<<dim3(CLL / 16, NB), 256, 0, stream>>>(Wll, ll_pw, ll_pb, avll, Mll, mvll);
    k_pm<CHH><<<dim3(CHH / 16, NB), 256, 0, stream>>>(Whh, h_pw, h_pb, avhh, Mhh, mvhh);

    k_final<<<dim3(256, NB), 256, 0, stream>>>(xll, xhh, Mll, Mhh, mvll, mvhh, out);
}

// Round 3
// 543.967 us; speedup vs baseline: 2.0149x; 1.2284x over previous
//
#include <hip/hip_runtime.h>

typedef __bf16 bf16;
typedef bf16 bf16x8 __attribute__((ext_vector_type(8)));
typedef float f32x4 __attribute__((ext_vector_type(4)));

#define NB 16
#define CLL 64
#define CHH 192
#define NPIX 16384

// ---------------- DWT: img(f32) -> X_ll, X_hh (bf16, [b][c][n]) + channel sums ----------------
__global__ __launch_bounds__(256) void k_dwt(const float* __restrict__ img, bf16* __restrict__ xll,
                      bf16* __restrict__ xhh, float* __restrict__ sll, float* __restrict__ shh) {
    int bc = blockIdx.y;           // b*64 + c
    int b = bc >> 6, c = bc & 63;
    int t = threadIdx.x;
    int r = blockIdx.x * 16 + (t >> 4);   // out row 0..127
    int q = t & 15;                        // 8-px col group
    const float* p0 = img + ((size_t)bc << 16) + (size_t)(2 * r) * 256 + 16 * q;
    const float* p1 = p0 + 256;
    float4 e0[4], e1[4];
    #pragma unroll
    for (int l = 0; l < 4; l++) { e0[l] = ((const float4*)p0)[l]; e1[l] = ((const float4*)p1)[l]; }
    const float* f0 = (const float*)e0;
    const float* f1 = (const float*)e1;
    bf16x8 vll, v1, v2, v3;
    float s0 = 0.f, s1 = 0.f, s2 = 0.f, s3 = 0.f;
    #pragma unroll
    for (int p = 0; p < 8; p++) {
        float a = f0[2 * p], bb = f0[2 * p + 1], cc = f1[2 * p], d = f1[2 * p + 1];
        float wll = (a + bb + cc + d) * 0.5f;
        float w1  = (a - bb + cc - d) * 0.5f;
        float w2  = (a + bb - cc - d) * 0.5f;
        float w3  = (a - bb - cc + d) * 0.5f;
        vll[p] = (bf16)wll; v1[p] = (bf16)w1; v2[p] = (bf16)w2; v3[p] = (bf16)w3;
        s0 += wll; s1 += w1; s2 += w2; s3 += w3;
    }
    size_t n = (size_t)r * 128 + 8 * q;
    *(bf16x8*)(xll + ((size_t)b * CLL + c) * NPIX + n) = vll;
    size_t hb = ((size_t)b * CHH + 3 * c) * NPIX + n;
    *(bf16x8*)(xhh + hb) = v1;
    *(bf16x8*)(xhh + hb + NPIX) = v2;
    *(bf16x8*)(xhh + hb + 2 * NPIX) = v3;
    for (int o = 32; o; o >>= 1) {
        s0 += __shfl_down(s0, o); s1 += __shfl_down(s1, o);
        s2 += __shfl_down(s2, o); s3 += __shfl_down(s3, o);
    }
    if ((t & 63) == 0) {
        atomicAdd(&sll[b * CLL + c], s0);
        atomicAdd(&shh[b * CHH + 3 * c + 0], s1);
        atomicAdd(&shh[b * CHH + 3 * c + 1], s2);
        atomicAdd(&shh[b * CHH + 3 * c + 2], s3);
    }
}

// ---------------- Gram: G[b] = X_b * X_b^T, upper-tri tiles only, LDS-staged ----------------
// 64x64 output tile per block (4 waves, each a 32x32 quadrant), BK=64 K-chunks,
// reg-staged global->LDS with XOR chunk-swizzle (chunk ^ (row&7)) for conflict-free ds_read_b128.
template <int C, int SPLITK>
__global__ __launch_bounds__(256) void k_gram(const bf16* __restrict__ X, float* __restrict__ G) {
    constexpr int T = C / 64;
    constexpr int NT = T * (T + 1) / 2;
    constexpr int KC = NPIX / SPLITK;
    __shared__ bf16 sA[64 * 64];
    __shared__ bf16 sB[64 * 64];
    int id = blockIdx.x;
    int sk = id % SPLITK; id /= SPLITK;
    int tl = id % NT;     id /= NT;
    int b = id;
    int ti = 0, tt = tl;
    while (tt >= T - ti) { tt -= T - ti; ti++; }
    int tj = ti + tt;
    const bf16* Xb = X + (size_t)b * C * NPIX;
    int t = threadIdx.x;
    int lane = t & 63, wv = t >> 6;
    int g = lane >> 4, l15 = lane & 15;

    // staging addresses: thread handles rows (t>>3) and (t>>3)+32 of each panel, chunk t&7
    int rowi = t >> 3, chunk = t & 7;
    int k0 = sk * KC;
    const bf16* gA0 = Xb + (size_t)(ti * 64 + rowi) * NPIX + k0 + chunk * 8;
    const bf16* gA1 = gA0 + (size_t)32 * NPIX;
    const bf16* gB0 = Xb + (size_t)(tj * 64 + rowi) * NPIX + k0 + chunk * 8;
    const bf16* gB1 = gB0 + (size_t)32 * NPIX;
    int swc = (chunk ^ (rowi & 7)) * 8;
    bf16* lA0 = sA + rowi * 64 + swc;
    bf16* lA1 = sA + (rowi + 32) * 64 + swc;   // (rowi+32)&7 == rowi&7
    bf16* lB0 = sB + rowi * 64 + swc;
    bf16* lB1 = sB + (rowi + 32) * 64 + swc;

    int arow = (wv >> 1) * 32;   // wave's quadrant
    int bcol = (wv & 1) * 32;
    int sw = l15 & 7;
    int roA0 = (arow + l15) * 64, roA1 = roA0 + 16 * 64;
    int roB0 = (bcol + l15) * 64, roB1 = roB0 + 16 * 64;

    f32x4 acc[2][2] = {};
    bf16x8 rA0 = *(const bf16x8*)gA0;
    bf16x8 rA1 = *(const bf16x8*)gA1;
    bf16x8 rB0 = *(const bf16x8*)gB0;
    bf16x8 rB1 = *(const bf16x8*)gB1;
    for (int kc = 0; kc < KC; kc += 64) {
        *(bf16x8*)lA0 = rA0; *(bf16x8*)lA1 = rA1;
        *(bf16x8*)lB0 = rB0; *(bf16x8*)lB1 = rB1;
        __syncthreads();
        if (kc + 64 < KC) {
            rA0 = *(const bf16x8*)(gA0 + kc + 64);
            rA1 = *(const bf16x8*)(gA1 + kc + 64);
            rB0 = *(const bf16x8*)(gB0 + kc + 64);
            rB1 = *(const bf16x8*)(gB1 + kc + 64);
        }
        #pragma unroll
        for (int ks = 0; ks < 2; ks++) {
            int ck = ((ks * 4 + g) ^ sw) * 8;
            bf16x8 a0 = *(const bf16x8*)(sA + roA0 + ck);
            bf16x8 a1 = *(const bf16x8*)(sA + roA1 + ck);
            bf16x8 b0 = *(const bf16x8*)(sB + roB0 + ck);
            bf16x8 b1 = *(const bf16x8*)(sB + roB1 + ck);
            acc[0][0] = __builtin_amdgcn_mfma_f32_16x16x32_bf16(a0, b0, acc[0][0], 0, 0, 0);
            acc[0][1] = __builtin_amdgcn_mfma_f32_16x16x32_bf16(a0, b1, acc[0][1], 0, 0, 0);
            acc[1][0] = __builtin_amdgcn_mfma_f32_16x16x32_bf16(a1, b0, acc[1][0], 0, 0, 0);
            acc[1][1] = __builtin_amdgcn_mfma_f32_16x16x32_bf16(a1, b1, acc[1][1], 0, 0, 0);
        }
        __syncthreads();
    }
    float* Gb = G + (size_t)b * C * C;
    int r0q = ti * 64 + arow;
    int c0q = tj * 64 + bcol;
    #pragma unroll
    for (int rr = 0; rr < 2; rr++)
        #pragma unroll
        for (int c2 = 0; c2 < 2; c2++)
            #pragma unroll
            for (int rg = 0; rg < 4; rg++) {
                int row = r0q + rr * 16 + g * 4 + rg;   // m89-verified C/D layout
                int col = c0q + c2 * 16 + l15;
                atomicAdd(&Gb[(size_t)row * C + col], acc[rr][c2][rg]);
            }
}

// mirror upper triangle to lower: G[i][j] = G[j][i] for i>j
template <int C>
__global__ void k_sym(float* __restrict__ G) {
    int b = blockIdx.y;
    float* Gb = G + (size_t)b * C * C;
    int idx = blockIdx.x * 256 + threadIdx.x;
    if (idx >= C * C) return;
    int i = idx / C, j = idx % C;
    if (j < i) Gb[idx] = Gb[(size_t)j * C + i];
}

// ---------------- P = w*G (per batch), plus row norm^2 and w·s ------------------------------
template <int C>
__global__ void k_pr(const float* __restrict__ G, const float* __restrict__ w,
                     const float* __restrict__ wb, const float* __restrict__ s,
                     float* __restrict__ P, float* __restrict__ nrm, float* __restrict__ wsum) {
    int b = blockIdx.y;
    int r0 = blockIdx.x * 16;
    int t = threadIdx.x, ti = t >> 4, tj = t & 15;
    int i = r0 + ti;
    const float* Gb = G + (size_t)b * C * C;
    constexpr int NJ = C / 16;
    float acc[NJ] = {};
    const float* wi = w + (size_t)i * C;
    for (int k = 0; k < C; k++) {
        float wk = wi[k];
        const float* Gk = Gb + (size_t)k * C;
        #pragma unroll
        for (int jj = 0; jj < NJ; jj++) acc[jj] += wk * Gk[tj + jj * 16];
    }
    float* Pb = P + (size_t)b * C * C;
    #pragma unroll
    for (int jj = 0; jj < NJ; jj++) Pb[(size_t)i * C + tj + jj * 16] = acc[jj];
    float np = 0.f;
    #pragma unroll
    for (int jj = 0; jj < NJ; jj++) np += acc[jj] * wi[tj + jj * 16];
    for (int o = 8; o; o >>= 1) np += __shfl_xor(np, o, 16);
    if (tj == 0) {
        float sd = 0.f; const float* sb = s + b * C;
        for (int k = 0; k < C; k++) sd += wi[k] * sb[k];
        float q2 = np + 2.f * wb[i] * sd + (float)NPIX * wb[i] * wb[i];
        nrm[b * C + i] = fmaxf(sqrtf(fmaxf(q2, 0.f)), 1e-12f);
        wsum[b * C + i] = sd;
    }
}

// ---------------- logits + softmax -> A, and av = A*vb --------------------------------------
template <int C>
__global__ void k_attn(const float* __restrict__ P, const float* __restrict__ kw,
                       const float* __restrict__ kb, const float* __restrict__ qb,
                       const float* __restrict__ qn, const float* __restrict__ kn,
                       const float* __restrict__ qs, const float* __restrict__ ks,
                       const float* __restrict__ vb, const float* __restrict__ temp,
                       float* __restrict__ A, float* __restrict__ av) {
    int b = blockIdx.y;
    int r0 = blockIdx.x * 16;
    int t = threadIdx.x, ti = t >> 4, tj = t & 15;
    int i = r0 + ti;
    constexpr int NJ = C / 16;
    const float* Pi = P + (size_t)b * C * C + (size_t)i * C;
    float L[NJ] = {};
    for (int k = 0; k < C; k++) {
        float pk = Pi[k];
        #pragma unroll
        for (int jj = 0; jj < NJ; jj++) L[jj] += pk * kw[(size_t)(tj + jj * 16) * C + k];
    }
    float qni = qn[b * C + i], qsi = qs[b * C + i], qbi = qb[i];
    float tmp = temp[0];
    #pragma unroll
    for (int jj = 0; jj < NJ; jj++) {
        int j = tj + jj * 16;
        float l = L[jj] + qsi * kb[j] + qbi * ks[b * C + j] + (float)NPIX * qbi * kb[j];
        L[jj] = l / (qni * kn[b * C + j]) * tmp;
    }
    float mx = -1e30f;
    #pragma unroll
    for (int jj = 0; jj < NJ; jj++) mx = fmaxf(mx, L[jj]);
    for (int o = 8; o; o >>= 1) mx = fmaxf(mx, __shfl_xor(mx, o, 16));
    float sum = 0.f;
    #pragma unroll
    for (int jj = 0; jj < NJ; jj++) { L[jj] = expf(L[jj] - mx); sum += L[jj]; }
    for (int o = 8; o; o >>= 1) sum += __shfl_xor(sum, o, 16);
    float inv = 1.f / sum;
    float* Ab = A + (size_t)b * C * C;
    float avp = 0.f;
    #pragma unroll
    for (int jj = 0; jj < NJ; jj++) {
        int j = tj + jj * 16;
        float a = L[jj] * inv;
        Ab[(size_t)i * C + j] = a;
        avp += a * vb[j];
    }
    for (int o = 8; o; o >>= 1) avp += __shfl_xor(avp, o, 16);
    if (tj == 0) av[b * C + i] = avp;
}

// ---------------- W = A*vw ------------------------------------------------------------------
template <int C>
__global__ void k_av(const float* __restrict__ A, const float* __restrict__ vw,
                     float* __restrict__ W) {
    int b = blockIdx.y;
    int r0 = blockIdx.x * 16;
    int t = threadIdx.x, ti = t >> 4, tj = t & 15;
    int i = r0 + ti;
    constexpr int NJ = C / 16;
    const float* Ai = A + (size_t)b * C * C + (size_t)i * C;
    float acc[NJ] = {};
    for (int k = 0; k < C; k++) {
        float a = Ai[k];
        const float* vr = vw + (size_t)k * C;
        #pragma unroll
        for (int jj = 0; jj < NJ; jj++) acc[jj] += a * vr[tj + jj * 16];
    }
    float* Wb = W + (size_t)b * C * C;
    #pragma unroll
    for (int jj = 0; jj < NJ; jj++) Wb[(size_t)i * C + tj + jj * 16] = acc[jj];
}

// ---------------- M = pw*W (bf16 out), mv = pw*av + pb --------------------------------------
template <int C>
__global__ void k_pm(const float* __restrict__ W, const float* __restrict__ pw,
                     const float* __restrict__ pb, const float* __restrict__ av,
                     bf16* __restrict__ M, float* __restrict__ mv) {
    int b = blockIdx.y;
    int r0 = blockIdx.x * 16;
    int t = threadIdx.x, ti = t >> 4, tj = t & 15;
    int i = r0 + ti;
    constexpr int NJ = C / 16;
    const float* pwi = pw + (size_t)i * C;
    const float* Wb = W + (size_t)b * C * C;
    float acc[NJ] = {};
    for (int k = 0; k < C; k++) {
        float p = pwi[k];
        const float* Wr = Wb + (size_t)k * C;
        #pragma unroll
        for (int jj = 0; jj < NJ; jj++) acc[jj] += p * Wr[tj + jj * 16];
    }
    bf16* Mb = M + (size_t)b * C * C;
    #pragma unroll
    for (int jj = 0; jj < NJ; jj++) Mb[(size_t)i * C + tj + jj * 16] = (bf16)acc[jj];
    if (tj == 0) {
        float m = pb[i];
        const float* avb = av + b * C;
        for (int k = 0; k < C; k++) m += pwi[k] * avb[k];
        mv[b * C + i] = m;
    }
}

// ---------------- Final: Y = M*X + mv (ll & hh), fused IDWT, write out ----------------------
__global__ __launch_bounds__(256) void k_final(const bf16* __restrict__ xll, const bf16* __restrict__ xhh,
                        const bf16* __restrict__ Mll, const bf16* __restrict__ Mhh,
                        const float* __restrict__ mvll, const float* __restrict__ mvhh,
                        float* __restrict__ out) {
    __shared__ alignas(16) float smemf[16384];   // 64 KB, aliased
    bf16* xtll = (bf16*)smemf;                    // [64 px][72]  (pad 8)
    bf16* xthh = (bf16*)((char*)smemf + 64 * 72 * 2);  // [64 px][200] (pad 8)
    float* Y = smemf;                             // [256 rows][64 px] after barrier
    int b = blockIdx.y, tile = blockIdx.x;
    int irow = tile >> 1, j0 = (tile & 1) << 6;
    int n0 = irow * 128 + j0;
    int t = threadIdx.x;
    const bf16* Xl = xll + (size_t)b * CLL * NPIX;
    const bf16* Xh = xhh + (size_t)b * CHH * NPIX;
    for (int task = t; task < 512; task += 256) {      // ll: 64 rows x 8 chunks
        int row = task >> 3, ch = task & 7;
        bf16x8 v = *(const bf16x8*)(Xl + (size_t)row * NPIX + n0 + ch * 8);
        #pragma unroll
        for (int p = 0; p < 8; p++) xtll[(ch * 8 + p) * 72 + row] = v[p];
    }
    for (int task = t; task < 1536; task += 256) {     // hh: 192 rows x 8 chunks
        int row = task >> 3, ch = task & 7;
        bf16x8 v = *(const bf16x8*)(Xh + (size_t)row * NPIX + n0 + ch * 8);
        #pragma unroll
        for (int p = 0; p < 8; p++) xthh[(ch * 8 + p) * 200 + row] = v[p];
    }
    __syncthreads();
    int wv = t >> 6, lane = t & 63, g = lane >> 4, l15 = lane & 15;
    f32x4 acc[4][4] = {};
    if (wv == 0) {
        const bf16* M = Mll + (size_t)b * CLL * CLL;
        for (int kb = 0; kb < CLL; kb += 32) {
            bf16x8 af[4], bfr[4];
            #pragma unroll
            for (int r = 0; r < 4; r++) af[r] = *(const bf16x8*)(M + (size_t)(r * 16 + l15) * CLL + kb + g * 8);
            #pragma unroll
            for (int c2 = 0; c2 < 4; c2++) bfr[c2] = *(const bf16x8*)(xtll + (c2 * 16 + l15) * 72 + kb + g * 8);
            #pragma unroll
            for (int r = 0; r < 4; r++)
                #pragma unroll
                for (int c2 = 0; c2 < 4; c2++)
                    acc[r][c2] = __builtin_amdgcn_mfma_f32_16x16x32_bf16(af[r], bfr[c2], acc[r][c2], 0, 0, 0);
        }
    } else {
        int wr = (wv - 1) * 64;
        const bf16* M = Mhh + (size_t)b * CHH * CHH;
        for (int kb = 0; kb < CHH; kb += 32) {
            bf16x8 af[4], bfr[4];
            #pragma unroll
            for (int r = 0; r < 4; r++) af[r] = *(const bf16x8*)(M + (size_t)(wr + r * 16 + l15) * CHH + kb + g * 8);
            #pragma unroll
            for (int c2 = 0; c2 < 4; c2++) bfr[c2] = *(const bf16x8*)(xthh + (c2 * 16 + l15) * 200 + kb + g * 8);
            #pragma unroll
            for (int r = 0; r < 4; r++)
                #pragma unroll
                for (int c2 = 0; c2 < 4; c2++)
                    acc[r][c2] = __builtin_amdgcn_mfma_f32_16x16x32_bf16(af[r], bfr[c2], acc[r][c2], 0, 0, 0);
        }
    }
    __syncthreads();   // staging reads done; smem becomes Y
    {
        int rbase = (wv == 0) ? 0 : 64 + (wv - 1) * 64;
        #pragma unroll
        for (int r = 0; r < 4; r++)
            #pragma unroll
            for (int c2 = 0; c2 < 4; c2++)
                #pragma unroll
                for (int rg = 0; rg < 4; rg++) {
                    int rl = r * 16 + g * 4 + rg;                 // row within wave's 64
                    float bias = (wv == 0) ? mvll[b * CLL + rl]
                                           : mvhh[b * CHH + (wv - 1) * 64 + rl];
                    Y[(rbase + rl) * 64 + c2 * 16 + l15] = acc[r][c2][rg] + bias;
                }
    }
    __syncthreads();
    int p = t & 63, cg = t >> 6;
    float* ob = out + ((size_t)b * CLL) * 65536;
    for (int it = 0; it < 16; it++) {
        int c = it * 4 + cg;
        float ll = Y[c * 64 + p];
        float h1 = Y[(64 + 3 * c + 0) * 64 + p];
        float h2 = Y[(64 + 3 * c + 1) * 64 + p];
        float h3 = Y[(64 + 3 * c + 2) * 64 + p];
        float a  = (ll + h1 + h2 + h3) * 0.5f;
        float bb = (ll - h1 + h2 - h3) * 0.5f;
        float cc = (ll + h1 - h2 - h3) * 0.5f;
        float d  = (ll - h1 - h2 + h3) * 0.5f;
        int jj = j0 + p;
        float2* o0 = (float2*)(ob + ((size_t)c * 256 + 2 * irow) * 256 + 2 * jj);
        float2* o1 = (float2*)(ob + ((size_t)c * 256 + 2 * irow + 1) * 256 + 2 * jj);
        *o0 = make_float2(a, bb);
        *o1 = make_float2(cc, d);
    }
}

extern "C" void kernel_launch(void* const* d_in, const int* in_sizes, int n_in,
                              void* d_out, int out_size, void* d_ws, size_t ws_size,
                              hipStream_t stream) {
    const float* img    = (const float*)d_in[0];
    // dict order is interleaved: ll_qw, h_qw, ll_qb, h_qb, ...
    const float* ll_qw = (const float*)d_in[1];  const float* h_qw = (const float*)d_in[2];
    const float* ll_qb = (const float*)d_in[3];  const float* h_qb = (const float*)d_in[4];
    const float* ll_kw = (const float*)d_in[5];  const float* h_kw = (const float*)d_in[6];
    const float* ll_kb = (const float*)d_in[7];  const float* h_kb = (const float*)d_in[8];
    const float* ll_vw = (const float*)d_in[9];  const float* h_vw = (const float*)d_in[10];
    const float* ll_vb = (const float*)d_in[11]; const float* h_vb = (const float*)d_in[12];
    const float* ll_pw = (const float*)d_in[13]; const float* h_pw = (const float*)d_in[14];
    const float* ll_pb = (const float*)d_in[15]; const float* h_pb = (const float*)d_in[16];
    const float* ll_tp = (const float*)d_in[17]; const float* h_tp = (const float*)d_in[18];
    float* out = (float*)d_out;

    char* ws = (char*)d_ws;
    size_t off = 0;
    auto alloc = [&](size_t sz) { char* p = ws + off; off += (sz + 255) & ~(size_t)255; return p; };
    bf16*  xll  = (bf16*) alloc((size_t)NB * CLL * NPIX * 2);
    bf16*  xhh  = (bf16*) alloc((size_t)NB * CHH * NPIX * 2);
    char*  zb   = ws + off;                       // zero-init region start
    float* sll  = (float*)alloc(NB * CLL * 4);
    float* shh  = (float*)alloc(NB * CHH * 4);
    float* Gll  = (float*)alloc((size_t)NB * CLL * CLL * 4);
    float* Ghh  = (float*)alloc((size_t)NB * CHH * CHH * 4);
    size_t zsz  = (size_t)((ws + off) - zb);
    float* Pll  = (float*)alloc((size_t)NB * CLL * CLL * 4);
    float* Phh  = (float*)alloc((size_t)NB * CHH * CHH * 4);
    float* Rll  = (float*)alloc((size_t)NB * CLL * CLL * 4);
    float* Rhh  = (float*)alloc((size_t)NB * CHH * CHH * 4);
    float* qnll = (float*)alloc(NB * CLL * 4);   float* qnhh = (float*)alloc(NB * CHH * 4);
    float* knll = (float*)alloc(NB * CLL * 4);   float* knhh = (float*)alloc(NB * CHH * 4);
    float* qsll = (float*)alloc(NB * CLL * 4);   float* qshh = (float*)alloc(NB * CHH * 4);
    float* ksll = (float*)alloc(NB * CLL * 4);   float* kshh = (float*)alloc(NB * CHH * 4);
    float* All  = (float*)alloc((size_t)NB * CLL * CLL * 4);
    float* Ahh  = (float*)alloc((size_t)NB * CHH * CHH * 4);
    float* avll = (float*)alloc(NB * CLL * 4);   float* avhh = (float*)alloc(NB * CHH * 4);
    float* Wll  = (float*)alloc((size_t)NB * CLL * CLL * 4);
    float* Whh  = (float*)alloc((size_t)NB * CHH * CHH * 4);
    bf16*  Mll  = (bf16*) alloc((size_t)NB * CLL * CLL * 2);
    bf16*  Mhh  = (bf16*) alloc((size_t)NB * CHH * CHH * 2);
    float* mvll = (float*)alloc(NB * CLL * 4);   float* mvhh = (float*)alloc(NB * CHH * 4);

    hipMemsetAsync(zb, 0, zsz, stream);

    k_dwt<<<dim3(8, NB * 64), 256, 0, stream>>>(img, xll, xhh, sll, shh);

    k_gram<CLL, 16><<<NB * 1 * 16, 256, 0, stream>>>(xll, Gll);
    k_gram<CHH, 8><<<NB * 6 * 8, 256, 0, stream>>>(xhh, Ghh);
    k_sym<CLL><<<dim3((CLL * CLL + 255) / 256, NB), 256, 0, stream>>>(Gll);
    k_sym<CHH><<<dim3((CHH * CHH + 255) / 256, NB), 256, 0, stream>>>(Ghh);

    k_pr<CLL><<<dim3(CLL / 16, NB), 256, 0, stream>>>(Gll, ll_qw, ll_qb, sll, Pll, qnll, qsll);
    k_pr<CLL><<<dim3(CLL / 16, NB), 256, 0, stream>>>(Gll, ll_kw, ll_kb, sll, Rll, knll, ksll);
    k_pr<CHH><<<dim3(CHH / 16, NB), 256, 0, stream>>>(Ghh, h_qw, h_qb, shh, Phh, qnhh, qshh);
    k_pr<CHH><<<dim3(CHH / 16, NB), 256, 0, stream>>>(Ghh, h_kw, h_kb, shh, Rhh, knhh, kshh);

    k_attn<CLL><<<dim3(CLL / 16, NB), 256, 0, stream>>>(Pll, ll_kw, ll_kb, ll_qb, qnll, knll,
                                                        qsll, ksll, ll_vb, ll_tp, All, avll);
    k_attn<CHH><<<dim3(CHH / 16, NB), 256, 0, stream>>>(Phh, h_kw, h_kb, h_qb, qnhh, knhh,
                                                        qshh, kshh, h_vb, h_tp, Ahh, avhh);

    k_av<CLL><<<dim3(CLL / 16, NB), 256, 0, stream>>>(All, ll_vw, Wll);
    k_av<CHH><<<dim3(CHH / 16, NB), 256, 0, stream>>>(Ahh, h_vw, Whh);

    k_pm<CLL><<<dim3(CLL / 16, NB), 256, 0, stream>>>(Wll, ll_pw, ll_pb, avll, Mll, mvll);
    k_pm<CHH><<<dim3(CHH / 16, NB), 256, 0, stream>>>(Whh, h_pw, h_pb, avhh, Mhh, mvhh);

    k_final<<<dim3(256, NB), 256, 0, stream>>>(xll, xhh, Mll, Mhh, mvll, mvhh, out);
}